// Round 1
// baseline (369.374 us; speedup 1.0000x reference)
//
#include <hip/hip_runtime.h>
#include <stdint.h>

#define NIMG 8
#define NCLS 80
#define HF 100
#define WF 152
#define NPTS (HF*WF)          // 15200
#define NPC (NPTS*NCLS)       // 1216000
#define TOPK 1000
#define CAP 2048
#define POSTK 100
#define SCAN_BLOCKS 297       // ceil(NPC/4096)

// ---- workspace layout (bytes) ----
static constexpr size_t B_H1    = 0;                          // u32 [8][4096]
static constexpr size_t B_H2    = B_H1 + (size_t)8*4096*4;    // u32 [8][4096]
static constexpr size_t B_CNT   = B_H2 + (size_t)8*4096*4;    // u32 [8]
static constexpr size_t B_META  = B_CNT + 8*4;                // u32 [8][4] {c_above,B,T24,-}
static constexpr size_t B_ZEND  = B_META + 8*4*4;             // memset 0 through here
static constexpr size_t B_CAND  = (B_ZEND + 7) & ~(size_t)7;  // u64 [8][CAP]
static constexpr size_t B_BOX   = B_CAND + (size_t)8*CAP*8;   // f32 [8][TOPK][4]
static constexpr size_t B_OBOX  = B_BOX + (size_t)8*TOPK*16;  // f32 [8][TOPK][4]
static constexpr size_t B_SC    = B_OBOX + (size_t)8*TOPK*16; // f32 [8][TOPK]
static constexpr size_t B_VAL   = B_SC + (size_t)8*TOPK*4;    // u32 [8][TOPK]
static constexpr size_t B_LAB   = B_VAL + (size_t)8*TOPK*4;   // u32 [8][TOPK]
static constexpr size_t B_CBASE = B_LAB + (size_t)8*TOPK*4;   // u32 [8][81]
static constexpr size_t B_CLIST = B_CBASE + (size_t)8*81*4;   // u32 [8][TOPK]
static constexpr size_t B_KEEP  = B_CLIST + (size_t)8*TOPK*4; // u32 [8][TOPK]

__device__ __forceinline__ float sigm(float x){ return 1.0f / (1.0f + expf(-x)); }

// score for input-layout element e = c*NPTS + p; f = reference flat index p*NCLS + c
__device__ __forceinline__ float score_at(const float* __restrict__ cls,
                                          const float* __restrict__ ctr,
                                          int e, uint32_t& f){
  int c = e / NPTS;
  int p = e - c * NPTS;
  f = (uint32_t)(p * NCLS + c);
  float s = sigm(cls[e]);
  if (!(s > 0.05f)) return 0.0f;          // cand = cls > PRE_NMS_THRESH
  return s * sigm(ctr[p]);                // cls * centerness
}

__global__ void k_hist1(const float* __restrict__ box_cls, const float* __restrict__ ctr,
                        uint32_t* __restrict__ h1){
  __shared__ uint32_t h[4096];
  for (int i = threadIdx.x; i < 4096; i += 256) h[i] = 0;
  __syncthreads();
  const int n = blockIdx.y;
  const float* cls = box_cls + (size_t)n * NPC;
  const float* ct  = ctr + (size_t)n * NPTS;
  const int base = blockIdx.x * 4096;
  for (int k = 0; k < 16; ++k){
    int e = base + k * 256 + threadIdx.x;
    if (e < NPC){
      uint32_t f; float s = score_at(cls, ct, e, f);
      if (s > 0.0f) atomicAdd(&h[__float_as_uint(s) >> 20], 1u);
    }
  }
  __syncthreads();
  uint32_t* g = h1 + (size_t)n * 4096;
  for (int i = threadIdx.x; i < 4096; i += 256){
    uint32_t v = h[i];
    if (v) atomicAdd(&g[i], v);
  }
}

__global__ void k_scan1(const uint32_t* __restrict__ h1, uint32_t* __restrict__ meta){
  const int n = blockIdx.x;
  const uint32_t* h = h1 + (size_t)n * 4096;
  __shared__ uint32_t psum[256];
  __shared__ uint32_t suff[256];
  const int t = threadIdx.x;
  uint32_t s = 0;
  #pragma unroll
  for (int i = 0; i < 16; ++i) s += h[t * 16 + i];
  psum[t] = s;
  __syncthreads();
  if (t == 0){
    uint32_t acc = 0;
    for (int seg = 255; seg >= 0; --seg){ suff[seg] = acc; acc += psum[seg]; }
  }
  __syncthreads();
  if (suff[t] < TOPK && suff[t] + psum[t] >= TOPK){
    uint32_t acc = suff[t];
    for (int b = t * 16 + 15; b >= t * 16; --b){
      uint32_t hb = h[b];
      if (acc + hb >= TOPK){
        meta[n * 4 + 0] = acc;           // c_above (count strictly above bin B)
        meta[n * 4 + 1] = (uint32_t)b;   // B
        break;
      }
      acc += hb;
    }
  }
}

__global__ void k_hist2(const float* __restrict__ box_cls, const float* __restrict__ ctr,
                        const uint32_t* __restrict__ meta, uint32_t* __restrict__ h2){
  const int n = blockIdx.y;
  const uint32_t B = meta[n * 4 + 1];
  const float* cls = box_cls + (size_t)n * NPC;
  const float* ct  = ctr + (size_t)n * NPTS;
  uint32_t* g = h2 + (size_t)n * 4096;
  const int base = blockIdx.x * 4096;
  for (int k = 0; k < 16; ++k){
    int e = base + k * 256 + threadIdx.x;
    if (e < NPC){
      uint32_t f; float s = score_at(cls, ct, e, f);
      if (s > 0.0f){
        uint32_t bits = __float_as_uint(s);
        if ((bits >> 20) == B) atomicAdd(&g[(bits >> 8) & 4095u], 1u);
      }
    }
  }
}

__global__ void k_scan2(const uint32_t* __restrict__ h2, uint32_t* __restrict__ meta){
  const int n = blockIdx.x;
  const uint32_t* h = h2 + (size_t)n * 4096;
  __shared__ uint32_t psum[256];
  __shared__ uint32_t suff[256];
  const int t = threadIdx.x;
  uint32_t s = 0;
  #pragma unroll
  for (int i = 0; i < 16; ++i) s += h[t * 16 + i];
  psum[t] = s;
  __syncthreads();
  if (t == 0){
    uint32_t acc = 0;
    for (int seg = 255; seg >= 0; --seg){ suff[seg] = acc; acc += psum[seg]; }
  }
  __syncthreads();
  const uint32_t R = TOPK - meta[n * 4 + 0];   // remaining after c_above
  if (suff[t] < R && suff[t] + psum[t] >= R){
    uint32_t acc = suff[t];
    for (int b = t * 16 + 15; b >= t * 16; --b){
      uint32_t hb = h[b];
      if (acc + hb >= R){
        meta[n * 4 + 2] = (meta[n * 4 + 1] << 12) | (uint32_t)b;  // T24
        break;
      }
      acc += hb;
    }
  }
}

__global__ void k_collect(const float* __restrict__ box_cls, const float* __restrict__ ctr,
                          const uint32_t* __restrict__ meta,
                          uint32_t* __restrict__ cnt, uint64_t* __restrict__ cand){
  const int n = blockIdx.y;
  const uint32_t T24 = meta[n * 4 + 2];
  const float* cls = box_cls + (size_t)n * NPC;
  const float* ct  = ctr + (size_t)n * NPTS;
  const int base = blockIdx.x * 4096;
  for (int k = 0; k < 16; ++k){
    int e = base + k * 256 + threadIdx.x;
    if (e < NPC){
      uint32_t f; float s = score_at(cls, ct, e, f);
      if (s > 0.0f){
        uint32_t bits = __float_as_uint(s);
        if ((bits >> 8) >= T24){
          uint32_t pos = atomicAdd(&cnt[n], 1u);
          if (pos < CAP)
            cand[(size_t)n * CAP + pos] = ((uint64_t)bits << 32) | (uint64_t)(0xFFFFFFFFu - f);
        }
      }
    }
  }
}

// sort candidates (value desc, index asc), take top-1000, decode boxes
__global__ void __launch_bounds__(1024)
k_sort_decode(const uint32_t* __restrict__ cnt, const uint64_t* __restrict__ cand,
              const float* __restrict__ locations, const float* __restrict__ box_reg,
              const float* __restrict__ im_info,
              float* __restrict__ boxw, float* __restrict__ oboxw, float* __restrict__ scw,
              uint32_t* __restrict__ valw, uint32_t* __restrict__ labw){
  __shared__ uint64_t key[2048];
  const int n = blockIdx.x;
  const int t = threadIdx.x;
  int nc = (int)cnt[n]; if (nc > CAP) nc = CAP;
  const uint64_t* cd = cand + (size_t)n * CAP;
  key[t]        = (t < nc) ? cd[t] : 0ull;
  key[t + 1024] = (t + 1024 < nc) ? cd[t + 1024] : 0ull;
  __syncthreads();
  for (int k = 2; k <= 2048; k <<= 1){
    for (int j = k >> 1; j > 0; j >>= 1){
      #pragma unroll
      for (int m = 0; m < 2; ++m){
        int i = t + m * 1024;
        int ixj = i ^ j;
        if (ixj > i){
          uint64_t a = key[i], b = key[ixj];
          bool desc = ((i & k) == 0);
          bool sw = desc ? (a < b) : (a > b);
          if (sw){ key[i] = b; key[ixj] = a; }
        }
      }
      __syncthreads();
    }
  }
  if (t < TOPK){
    uint64_t kk = key[t];
    uint32_t bits = (uint32_t)(kk >> 32);
    uint32_t fi = 0xFFFFFFFFu - (uint32_t)(kk & 0xFFFFFFFFull);
    float v = __uint_as_float(bits);
    int loc = 0, ci = 0;
    if (v > 0.0f){ loc = (int)(fi / NCLS); ci = (int)(fi - (uint32_t)loc * NCLS); }
    float px = locations[2 * loc], py = locations[2 * loc + 1];
    const float* rg = box_reg + (size_t)n * 4 * NPTS;
    float rl = rg[loc], rt = rg[NPTS + loc], rr = rg[2 * NPTS + loc], rb = rg[3 * NPTS + loc];
    float h_im = im_info[n * 2 + 0], w_im = im_info[n * 2 + 1];
    float x1 = fminf(fmaxf(px - rl, 0.0f), w_im - 1.0f);
    float y1 = fminf(fmaxf(py - rt, 0.0f), h_im - 1.0f);
    float x2 = fminf(fmaxf(px + rr, 0.0f), w_im - 1.0f);
    float y2 = fminf(fmaxf(py + rb, 0.0f), h_im - 1.0f);
    bool valid = (v > 0.0f) && (__fsub_rn(x2, x1) >= 0.0f) && (__fsub_rn(y2, y1) >= 0.0f);
    float scv = valid ? v : 0.0f;
    float lab = (float)(ci + 1);
    float off = __fmul_rn(lab, 100000.0f);   // CLASS_OFFSET, mul then add (no fma) like ref
    size_t b4 = ((size_t)n * TOPK + t) * 4;
    boxw[b4 + 0] = x1; boxw[b4 + 1] = y1; boxw[b4 + 2] = x2; boxw[b4 + 3] = y2;
    oboxw[b4 + 0] = __fadd_rn(x1, off); oboxw[b4 + 1] = __fadd_rn(y1, off);
    oboxw[b4 + 2] = __fadd_rn(x2, off); oboxw[b4 + 3] = __fadd_rn(y2, off);
    size_t b1 = (size_t)n * TOPK + t;
    scw[b1] = scv; valw[b1] = valid ? 1u : 0u; labw[b1] = (uint32_t)(ci + 1);
  }
}

// stable partition of the 1000 sorted candidates by class label
__global__ void k_partition(const uint32_t* __restrict__ labw,
                            uint32_t* __restrict__ cbase, uint32_t* __restrict__ clist){
  const int n = blockIdx.x;
  __shared__ uint8_t lab_s[TOPK];
  __shared__ uint32_t cnt_s[NCLS];
  __shared__ uint32_t base_s[NCLS + 1];
  const int t = threadIdx.x;
  for (int i = t; i < NCLS; i += 256) cnt_s[i] = 0;
  __syncthreads();
  for (int i = t; i < TOPK; i += 256){
    uint8_t l = (uint8_t)(labw[n * TOPK + i] - 1);
    lab_s[i] = l;
    atomicAdd(&cnt_s[l], 1u);
  }
  __syncthreads();
  if (t == 0){
    uint32_t acc = 0;
    for (int c = 0; c < NCLS; ++c){ base_s[c] = acc; acc += cnt_s[c]; }
    base_s[NCLS] = acc;
  }
  __syncthreads();
  for (int i = t; i < TOPK; i += 256){
    uint8_t my = lab_s[i];
    uint32_t rank = 0;
    for (int j = 0; j < i; ++j) rank += (lab_s[j] == my) ? 1u : 0u;
    clist[n * TOPK + base_s[my] + rank] = (uint32_t)i;
  }
  for (int i = t; i < NCLS + 1; i += 256) cbase[n * (NCLS + 1) + i] = base_s[i];
}

// greedy NMS per (image,class); cross-class IoU is exactly 0 under the 1e5 offset
__global__ void __launch_bounds__(64)
k_nms(const uint32_t* __restrict__ cbase, const uint32_t* __restrict__ clist,
      const float* __restrict__ oboxw, const uint32_t* __restrict__ valw,
      uint32_t* __restrict__ keepw){
  const int n = blockIdx.y;
  const int c = blockIdx.x;
  const uint32_t base = cbase[n * (NCLS + 1) + c];
  const uint32_t kcnt = cbase[n * (NCLS + 1) + c + 1] - base;
  if (kcnt == 0) return;
  const int L = threadIdx.x;
  const uint32_t* lst = clist + (size_t)n * TOPK + base;
  if (kcnt <= 64){
    int gi = 0, kp = 0;
    float b0 = 0, b1 = 0, b2 = 0, b3 = 0, ar = 0;
    if (L < (int)kcnt){
      gi = (int)lst[L];
      size_t a4 = ((size_t)n * TOPK + gi) * 4;
      b0 = oboxw[a4 + 0]; b1 = oboxw[a4 + 1]; b2 = oboxw[a4 + 2]; b3 = oboxw[a4 + 3];
      kp = (valw[n * TOPK + gi] != 0) ? 1 : 0;
      ar = __fmul_rn(fmaxf(__fsub_rn(b2, b0), 0.0f), fmaxf(__fsub_rn(b3, b1), 0.0f));
    }
    for (int i = 0; i + 1 < (int)kcnt; ++i){
      int alive = __shfl(kp, i);
      float xi0 = __shfl(b0, i), xi1 = __shfl(b1, i), xi2 = __shfl(b2, i), xi3 = __shfl(b3, i);
      float ai = __shfl(ar, i);
      if (alive && L > i && kp){
        float ltx = fmaxf(xi0, b0), lty = fmaxf(xi1, b1);
        float rbx = fminf(xi2, b2), rby = fminf(xi3, b3);
        float w = fmaxf(__fsub_rn(rbx, ltx), 0.0f);
        float h = fmaxf(__fsub_rn(rby, lty), 0.0f);
        float inter = __fmul_rn(w, h);
        float den = __fadd_rn(__fsub_rn(__fadd_rn(ai, ar), inter), 1e-9f);
        if (inter / den > 0.6f) kp = 0;
      }
    }
    if (L < (int)kcnt) keepw[n * TOPK + gi] = (uint32_t)kp;
  } else if (L == 0){
    // slow path (kcnt > 64): sequential, correctness-only (statistically never hit)
    for (uint32_t i = 0; i < kcnt; ++i){
      int gi = (int)lst[i];
      keepw[n * TOPK + gi] = valw[n * TOPK + gi];
    }
    for (uint32_t i = 0; i < kcnt; ++i){
      int gi = (int)lst[i];
      if (!keepw[n * TOPK + gi]) continue;
      size_t a4 = ((size_t)n * TOPK + gi) * 4;
      float x0 = oboxw[a4], x1 = oboxw[a4 + 1], x2 = oboxw[a4 + 2], x3 = oboxw[a4 + 3];
      float ai = __fmul_rn(fmaxf(__fsub_rn(x2, x0), 0.0f), fmaxf(__fsub_rn(x3, x1), 0.0f));
      for (uint32_t j = i + 1; j < kcnt; ++j){
        int gj = (int)lst[j];
        if (!keepw[n * TOPK + gj]) continue;
        size_t c4 = ((size_t)n * TOPK + gj) * 4;
        float y0 = oboxw[c4], y1 = oboxw[c4 + 1], y2 = oboxw[c4 + 2], y3 = oboxw[c4 + 3];
        float aj = __fmul_rn(fmaxf(__fsub_rn(y2, y0), 0.0f), fmaxf(__fsub_rn(y3, y1), 0.0f));
        float ltx = fmaxf(x0, y0), lty = fmaxf(x1, y1);
        float rbx = fminf(x2, y2), rby = fminf(x3, y3);
        float w = fmaxf(__fsub_rn(rbx, ltx), 0.0f);
        float h = fmaxf(__fsub_rn(rby, lty), 0.0f);
        float inter = __fmul_rn(w, h);
        float den = __fadd_rn(__fsub_rn(__fadd_rn(ai, aj), inter), 1e-9f);
        if (inter / den > 0.6f) keepw[n * TOPK + gj] = 0;
      }
    }
  }
}

// compact kept (already score-sorted) entries; first 100 rows, rest zero
__global__ void k_final(const uint32_t* __restrict__ keepw, const float* __restrict__ boxw,
                        const uint32_t* __restrict__ labw, const float* __restrict__ scw,
                        float* __restrict__ out){
  const int n = blockIdx.x;
  __shared__ int fi_s[POSTK];
  __shared__ int cnt_s;
  if (threadIdx.x == 0){
    int cnt = 0;
    for (int i = 0; i < TOPK && cnt < POSTK; ++i)
      if (keepw[n * TOPK + i]) fi_s[cnt++] = i;
    cnt_s = cnt;
  }
  __syncthreads();
  const int t = threadIdx.x;
  if (t < POSTK){
    float* row = out + ((size_t)n * POSTK + t) * 6;
    if (t < cnt_s){
      int i = fi_s[t];
      size_t b4 = ((size_t)n * TOPK + i) * 4;
      row[0] = boxw[b4]; row[1] = boxw[b4 + 1]; row[2] = boxw[b4 + 2]; row[3] = boxw[b4 + 3];
      row[4] = (float)labw[n * TOPK + i]; row[5] = scw[n * TOPK + i];
    } else {
      row[0] = 0.0f; row[1] = 0.0f; row[2] = 0.0f;
      row[3] = 0.0f; row[4] = 0.0f; row[5] = 0.0f;
    }
  }
}

extern "C" void kernel_launch(void* const* d_in, const int* in_sizes, int n_in,
                              void* d_out, int out_size, void* d_ws, size_t ws_size,
                              hipStream_t stream){
  const float* locations = (const float*)d_in[0];
  const float* box_cls   = (const float*)d_in[1];
  const float* box_reg   = (const float*)d_in[2];
  const float* ctr       = (const float*)d_in[3];
  const float* im_info   = (const float*)d_in[4];
  float* out = (float*)d_out;
  char* ws = (char*)d_ws;
  uint32_t* h1    = (uint32_t*)(ws + B_H1);
  uint32_t* h2    = (uint32_t*)(ws + B_H2);
  uint32_t* cnt   = (uint32_t*)(ws + B_CNT);
  uint32_t* meta  = (uint32_t*)(ws + B_META);
  uint64_t* cand  = (uint64_t*)(ws + B_CAND);
  float*    boxw  = (float*)(ws + B_BOX);
  float*    oboxw = (float*)(ws + B_OBOX);
  float*    scw   = (float*)(ws + B_SC);
  uint32_t* valw  = (uint32_t*)(ws + B_VAL);
  uint32_t* labw  = (uint32_t*)(ws + B_LAB);
  uint32_t* cbase = (uint32_t*)(ws + B_CBASE);
  uint32_t* clist = (uint32_t*)(ws + B_CLIST);
  uint32_t* keepw = (uint32_t*)(ws + B_KEEP);

  hipMemsetAsync(d_ws, 0, B_ZEND, stream);
  dim3 scang(SCAN_BLOCKS, NIMG);
  k_hist1<<<scang, 256, 0, stream>>>(box_cls, ctr, h1);
  k_scan1<<<NIMG, 256, 0, stream>>>(h1, meta);
  k_hist2<<<scang, 256, 0, stream>>>(box_cls, ctr, meta, h2);
  k_scan2<<<NIMG, 256, 0, stream>>>(h2, meta);
  k_collect<<<scang, 256, 0, stream>>>(box_cls, ctr, meta, cnt, cand);
  k_sort_decode<<<NIMG, 1024, 0, stream>>>(cnt, cand, locations, box_reg, im_info,
                                           boxw, oboxw, scw, valw, labw);
  k_partition<<<NIMG, 256, 0, stream>>>(labw, cbase, clist);
  k_nms<<<dim3(NCLS, NIMG), 64, 0, stream>>>(cbase, clist, oboxw, valw, keepw);
  k_final<<<NIMG, 128, 0, stream>>>(keepw, boxw, labw, scw, out);
}